// Round 1
// baseline (312.119 us; speedup 1.0000x reference)
//
#include <hip/hip_runtime.h>

typedef short short8 __attribute__((ext_vector_type(8)));
typedef float f32x4 __attribute__((ext_vector_type(4)));
typedef float f32x16 __attribute__((ext_vector_type(16)));

#define NHEADS 8
#define DHEAD 32
#define DMODEL 256
#define BATCH 8
#define SEQ 2048
#define QSCALE 0.17677669529663687f /* 1/sqrt(32) */

__device__ __forceinline__ unsigned short f2bf(float x) {
  union { float f; unsigned int u; } c; c.f = x;
  return (unsigned short)((c.u + 0x7fffu + ((c.u >> 16) & 1u)) >> 16);
}
__device__ __forceinline__ unsigned int pack2bf(float lo, float hi) {
  return (unsigned int)f2bf(lo) | ((unsigned int)f2bf(hi) << 16);
}

// ---------------- prep: W^T bf16 (x4), scaled bq, mask bias ----------------
__global__ __launch_bounds__(256) void prep_kernel(
    const float* __restrict__ wq, const float* __restrict__ wk,
    const float* __restrict__ wv, const float* __restrict__ wo,
    const float* __restrict__ bq, const float* __restrict__ m,
    unsigned short* __restrict__ wt, float* __restrict__ bqs,
    float* __restrict__ maskb)
{
  int tid = blockIdx.x * 256 + threadIdx.x;
  if (tid < 4 * 65536) {
    int mi = tid >> 16, rem = tid & 65535;
    int k = rem >> 8, n = rem & 255;
    const float* w = (mi == 0) ? wq : (mi == 1) ? wk : (mi == 2) ? wv : wo;
    float v = w[k * 256 + n];
    if (mi == 0) v *= QSCALE;
    wt[mi * 65536 + n * 256 + k] = f2bf(v);
  } else if (tid < 4 * 65536 + SEQ) {
    int i = tid - 4 * 65536;
    maskb[i] = m[i] * -1e9f;
  } else if (tid < 4 * 65536 + SEQ + 256) {
    int i = tid - 4 * 65536 - SEQ;
    bqs[i] = bq[i] * QSCALE;
  }
}

// ---------------- Q/K projection: out [b][h][s][32] bf16 ----------------
__global__ __launch_bounds__(256) void proj_qk_kernel(
    const float* __restrict__ xq, const float* __restrict__ xk,
    const unsigned short* __restrict__ wt,  // wtq at +0, wtk at +65536
    const float* __restrict__ bqs, const float* __restrict__ bk,
    unsigned short* __restrict__ qh, unsigned short* __restrict__ kh)
{
  const int z = blockIdx.y;
  const int tile = blockIdx.x;  // 0..511, 32 rows each
  const int w = threadIdx.x >> 6, lane = threadIdx.x & 63;
  const int fr = lane & 15, hi = lane >> 4;  // hi: 0..3
  const float* x = z ? xk : xq;
  const unsigned short* wtz = wt + z * 65536;
  const float* bias = z ? bk : bqs;
  unsigned short* outp = z ? kh : qh;
  const int row = tile * 32 + (w & 1) * 16 + fr;
  const int colbase = (w >> 1) * 128;
  const float* xrow = x + (size_t)row * DMODEL;

  f32x4 acc[8];
  #pragma unroll
  for (int n = 0; n < 8; n++) { acc[n][0]=0.f; acc[n][1]=0.f; acc[n][2]=0.f; acc[n][3]=0.f; }

  for (int kk = 0; kk < DMODEL; kk += 32) {
    const float4* ap = (const float4*)(xrow + kk + 8 * hi);
    float4 a0 = ap[0], a1 = ap[1];
    short8 af;
    af[0]=(short)f2bf(a0.x); af[1]=(short)f2bf(a0.y); af[2]=(short)f2bf(a0.z); af[3]=(short)f2bf(a0.w);
    af[4]=(short)f2bf(a1.x); af[5]=(short)f2bf(a1.y); af[6]=(short)f2bf(a1.z); af[7]=(short)f2bf(a1.w);
    #pragma unroll
    for (int n = 0; n < 8; n++) {
      short8 bf = *(const short8*)(wtz + (size_t)(colbase + n * 16 + fr) * DMODEL + kk + 8 * hi);
      acc[n] = __builtin_amdgcn_mfma_f32_16x16x32_bf16(af, bf, acc[n], 0, 0, 0);
    }
  }

  const int orow0 = tile * 32 + (w & 1) * 16 + hi * 4;
  #pragma unroll
  for (int n = 0; n < 8; n++) {
    const int col = colbase + n * 16 + fr;
    const float bb = bias[col];
    const int h = col >> 5, d = col & 31;
    #pragma unroll
    for (int j = 0; j < 4; j++) {
      const int r = orow0 + j;
      const int b = r >> 11, s = r & 2047;
      outp[(size_t)((b * NHEADS + h) * SEQ + s) * DHEAD + d] = f2bf(acc[n][j] + bb);
    }
  }
}

// ------------- V projection, transposed out: Vt [b][h][32][S] bf16 -------------
__global__ __launch_bounds__(256) void proj_v_kernel(
    const float* __restrict__ xv, const unsigned short* __restrict__ wtv,
    const float* __restrict__ bv, unsigned short* __restrict__ vt)
{
  const int tile = blockIdx.x;  // 0..511, 32 tokens each
  const int w = threadIdx.x >> 6, lane = threadIdx.x & 63;
  const int fr = lane & 15, hi = lane >> 4;
  const int tokbase = tile * 32 + (w & 1) * 16;
  const int nbase = (w >> 1) * 128;
  const float* xrow = xv + (size_t)(tokbase + fr) * DMODEL;

  f32x4 acc[8];
  #pragma unroll
  for (int n = 0; n < 8; n++) { acc[n][0]=0.f; acc[n][1]=0.f; acc[n][2]=0.f; acc[n][3]=0.f; }

  for (int kk = 0; kk < DMODEL; kk += 32) {
    const float4* bp = (const float4*)(xrow + kk + 8 * hi);
    float4 b0 = bp[0], b1 = bp[1];
    short8 bfx;  // B = X^T fragment: col = token (fr), k = kk+8*hi+i
    bfx[0]=(short)f2bf(b0.x); bfx[1]=(short)f2bf(b0.y); bfx[2]=(short)f2bf(b0.z); bfx[3]=(short)f2bf(b0.w);
    bfx[4]=(short)f2bf(b1.x); bfx[5]=(short)f2bf(b1.y); bfx[6]=(short)f2bf(b1.z); bfx[7]=(short)f2bf(b1.w);
    #pragma unroll
    for (int n = 0; n < 8; n++) {
      short8 afw = *(const short8*)(wtv + (size_t)(nbase + n * 16 + fr) * DMODEL + kk + 8 * hi);
      acc[n] = __builtin_amdgcn_mfma_f32_16x16x32_bf16(afw, bfx, acc[n], 0, 0, 0);
    }
  }

  #pragma unroll
  for (int n = 0; n < 8; n++) {
    #pragma unroll
    for (int j = 0; j < 4; j++) {
      const int nrow = nbase + n * 16 + hi * 4 + j;  // output feature
      const int h = nrow >> 5, d = nrow & 31;
      const int tok = tokbase + fr;
      const int b = tok >> 11, s = tok & 2047;
      vt[(size_t)((b * NHEADS + h) * DHEAD + d) * SEQ + s] = f2bf(acc[n][j] + bv[nrow]);
    }
  }
}

// ---------------- fused flash attention ----------------
__global__ __launch_bounds__(256) void attn_kernel(
    const unsigned short* __restrict__ qh, const unsigned short* __restrict__ kh,
    const unsigned short* __restrict__ vt, const float* __restrict__ maskb,
    unsigned short* __restrict__ attno)
{
  const int bid = blockIdx.x;
  const int L = (bid & 7) * 128 + (bid >> 3);  // XCD swizzle (1024 % 8 == 0)
  const int bh = L >> 4, qt = L & 15;
  const int w = threadIdx.x >> 6, lane = threadIdx.x & 63;
  const int ql = lane & 31, hi = lane >> 5;
  const int qrow = qt * 128 + w * 32 + ql;
  const unsigned short* Qp = qh + ((size_t)bh * SEQ + qrow) * DHEAD;
  const unsigned short* Kp = kh + (size_t)bh * SEQ * DHEAD;
  const unsigned short* Vp = vt + (size_t)bh * DHEAD * SEQ + (size_t)ql * SEQ;  // row d = ql

  const short8 qf0 = *(const short8*)(Qp + 8 * hi);
  const short8 qf1 = *(const short8*)(Qp + 16 + 8 * hi);

  f32x16 oacc;
  #pragma unroll
  for (int i = 0; i < 16; i++) oacc[i] = 0.0f;
  float mrun = -1e30f, lrun = 0.0f;

  for (int kt = 0; kt < SEQ; kt += 32) {
    const unsigned short* krow = Kp + (size_t)(kt + ql) * DHEAD + 8 * hi;
    const short8 kf0 = *(const short8*)(krow);
    const short8 kf1 = *(const short8*)(krow + 16);
    f32x16 sacc;
    #pragma unroll
    for (int i = 0; i < 16; i++) sacc[i] = 0.0f;
    // swapped QK^T: D[key][q], col = lane&31 = q, row = (r&3)+8*(r>>2)+4*hi = key
    sacc = __builtin_amdgcn_mfma_f32_32x32x16_bf16(kf0, qf0, sacc, 0, 0, 0);
    sacc = __builtin_amdgcn_mfma_f32_32x32x16_bf16(kf1, qf1, sacc, 0, 0, 0);

    const float4 mb0 = *(const float4*)(maskb + kt + 4 * hi);
    const float4 mb1 = *(const float4*)(maskb + kt + 4 * hi + 8);
    const float4 mb2 = *(const float4*)(maskb + kt + 4 * hi + 16);
    const float4 mb3 = *(const float4*)(maskb + kt + 4 * hi + 24);
    float p[16];
    p[0]=sacc[0]+mb0.x;  p[1]=sacc[1]+mb0.y;  p[2]=sacc[2]+mb0.z;  p[3]=sacc[3]+mb0.w;
    p[4]=sacc[4]+mb1.x;  p[5]=sacc[5]+mb1.y;  p[6]=sacc[6]+mb1.z;  p[7]=sacc[7]+mb1.w;
    p[8]=sacc[8]+mb2.x;  p[9]=sacc[9]+mb2.y;  p[10]=sacc[10]+mb2.z; p[11]=sacc[11]+mb2.w;
    p[12]=sacc[12]+mb3.x; p[13]=sacc[13]+mb3.y; p[14]=sacc[14]+mb3.z; p[15]=sacc[15]+mb3.w;

    float tmax = p[0];
    #pragma unroll
    for (int i = 1; i < 16; i++) tmax = fmaxf(tmax, p[i]);
    tmax = fmaxf(tmax, __shfl_xor(tmax, 32));
    const float mnew = fmaxf(mrun, tmax);
    const float corr = __expf(mrun - mnew);
    float psum = 0.0f;
    #pragma unroll
    for (int i = 0; i < 16; i++) { p[i] = __expf(p[i] - mnew); psum += p[i]; }
    psum += __shfl_xor(psum, 32);
    lrun = lrun * corr + psum;
    mrun = mnew;
    #pragma unroll
    for (int i = 0; i < 16; i++) oacc[i] *= corr;

    // P -> bf16 b-frag: lane needs keys 8*hi+[0..7] per 16-key step.
    const unsigned int A0 = pack2bf(p[0], p[1]);
    const unsigned int A1 = pack2bf(p[2], p[3]);
    const unsigned int B0 = pack2bf(p[4], p[5]);
    const unsigned int B1 = pack2bf(p[6], p[7]);
    const unsigned int A2 = pack2bf(p[8], p[9]);
    const unsigned int A3 = pack2bf(p[10], p[11]);
    const unsigned int B2 = pack2bf(p[12], p[13]);
    const unsigned int B3 = pack2bf(p[14], p[15]);
    const unsigned int sA0 = __shfl_xor(A0, 32);
    const unsigned int sA1 = __shfl_xor(A1, 32);
    const unsigned int sB0 = __shfl_xor(B0, 32);
    const unsigned int sB1 = __shfl_xor(B1, 32);
    const unsigned int sA2 = __shfl_xor(A2, 32);
    const unsigned int sA3 = __shfl_xor(A3, 32);
    const unsigned int sB2 = __shfl_xor(B2, 32);
    const unsigned int sB3 = __shfl_xor(B3, 32);
    union { unsigned int u[4]; short8 v; } pb0, pb1;
    pb0.u[0] = hi ? sB0 : A0;
    pb0.u[1] = hi ? sB1 : A1;
    pb0.u[2] = hi ? B0 : sA0;
    pb0.u[3] = hi ? B1 : sA1;
    pb1.u[0] = hi ? sB2 : A2;
    pb1.u[1] = hi ? sB3 : A3;
    pb1.u[2] = hi ? B2 : sA2;
    pb1.u[3] = hi ? B3 : sA3;

    const short8 vf0 = *(const short8*)(Vp + kt + 8 * hi);
    const short8 vf1 = *(const short8*)(Vp + kt + 16 + 8 * hi);
    // swapped PV: O^T[d][q], col = lane&31 = q (matches softmax state)
    oacc = __builtin_amdgcn_mfma_f32_32x32x16_bf16(vf0, pb0.v, oacc, 0, 0, 0);
    oacc = __builtin_amdgcn_mfma_f32_32x32x16_bf16(vf1, pb1.v, oacc, 0, 0, 0);
  }

  const float inv = 1.0f / lrun;
  const int b = bh >> 3, h = bh & 7;
  unsigned short* orow = attno + ((size_t)(b * SEQ + qrow)) * DMODEL + h * DHEAD + 4 * hi;
  #pragma unroll
  for (int g = 0; g < 4; g++) {
    union { unsigned short us[4]; uint2 u2; } st;
    st.us[0] = f2bf(oacc[4 * g + 0] * inv);
    st.us[1] = f2bf(oacc[4 * g + 1] * inv);
    st.us[2] = f2bf(oacc[4 * g + 2] * inv);
    st.us[3] = f2bf(oacc[4 * g + 3] * inv);
    *(uint2*)(orow + 8 * g) = st.u2;
  }
}

// ---------------- output projection: fp32 out + bias ----------------
__global__ __launch_bounds__(256) void oproj_kernel(
    const unsigned short* __restrict__ attno, const unsigned short* __restrict__ wto,
    const float* __restrict__ bo, float* __restrict__ out)
{
  const int tile = blockIdx.x;  // 0..511
  const int w = threadIdx.x >> 6, lane = threadIdx.x & 63;
  const int fr = lane & 15, hi = lane >> 4;
  const int row = tile * 32 + (w & 1) * 16 + fr;
  const int colbase = (w >> 1) * 128;
  const unsigned short* arow = attno + (size_t)row * DMODEL;

  f32x4 acc[8];
  #pragma unroll
  for (int n = 0; n < 8; n++) { acc[n][0]=0.f; acc[n][1]=0.f; acc[n][2]=0.f; acc[n][3]=0.f; }

  for (int kk = 0; kk < DMODEL; kk += 32) {
    short8 af = *(const short8*)(arow + kk + 8 * hi);
    #pragma unroll
    for (int n = 0; n < 8; n++) {
      short8 bf = *(const short8*)(wto + (size_t)(colbase + n * 16 + fr) * DMODEL + kk + 8 * hi);
      acc[n] = __builtin_amdgcn_mfma_f32_16x16x32_bf16(af, bf, acc[n], 0, 0, 0);
    }
  }

  const int orow0 = tile * 32 + (w & 1) * 16 + hi * 4;
  #pragma unroll
  for (int n = 0; n < 8; n++) {
    const int col = colbase + n * 16 + fr;
    const float bb = bo[col];
    #pragma unroll
    for (int j = 0; j < 4; j++) {
      out[(size_t)(orow0 + j) * DMODEL + col] = acc[n][j] + bb;
    }
  }
}

extern "C" void kernel_launch(void* const* d_in, const int* in_sizes, int n_in,
                              void* d_out, int out_size, void* d_ws, size_t ws_size,
                              hipStream_t stream) {
  const float* q  = (const float*)d_in[0];
  const float* k  = (const float*)d_in[1];
  const float* v  = (const float*)d_in[2];
  const float* m  = (const float*)d_in[3];
  const float* wq = (const float*)d_in[4];
  const float* bq = (const float*)d_in[5];
  const float* wk = (const float*)d_in[6];
  const float* bk = (const float*)d_in[7];
  const float* wv = (const float*)d_in[8];
  const float* bv = (const float*)d_in[9];
  const float* wo = (const float*)d_in[10];
  const float* bo = (const float*)d_in[11];
  float* out = (float*)d_out;

  char* ws = (char*)d_ws;
  unsigned short* wt    = (unsigned short*)ws;            // 4 x 256x256 bf16 (512 KB)
  float* bqs            = (float*)(ws + 524288);          // 256 f32
  float* maskb          = (float*)(ws + 525312);          // 2048 f32
  unsigned short* qh    = (unsigned short*)(ws + 1048576);  // 8 MB
  unsigned short* kh    = qh + 4194304;                     // 8 MB
  unsigned short* vt    = kh + 4194304;                     // 8 MB
  unsigned short* attno = vt + 4194304;                     // 8 MB

  prep_kernel<<<dim3(1033), dim3(256), 0, stream>>>(wq, wk, wv, wo, bq, m, wt, bqs, maskb);
  proj_qk_kernel<<<dim3(512, 2), dim3(256), 0, stream>>>(q, k, wt, bqs, bk, qh, kh);
  proj_v_kernel<<<dim3(512), dim3(256), 0, stream>>>(v, wt + 2 * 65536, bv, vt);
  attn_kernel<<<dim3(1024), dim3(256), 0, stream>>>(qh, kh, vt, maskb, attno);
  oproj_kernel<<<dim3(512), dim3(256), 0, stream>>>(attno, wt + 3 * 65536, bo, out);
}

// Round 2
// 247.777 us; speedup vs baseline: 1.2597x; 1.2597x over previous
//
#include <hip/hip_runtime.h>

typedef short short8 __attribute__((ext_vector_type(8)));
typedef float f32x4 __attribute__((ext_vector_type(4)));
typedef float f32x16 __attribute__((ext_vector_type(16)));
typedef unsigned int uint2v __attribute__((ext_vector_type(2)));

#define NHEADS 8
#define DHEAD 32
#define DMODEL 256
#define SEQ 2048
#define QSCALE 0.17677669529663687f /* 1/sqrt(32) */
#define LOG2E 1.4426950408889634f
#define NEGBIG -1.4427e9f            /* -1e9 * log2e, value only needs to underflow exp2 */
#define DEFER_THR 11.0f              /* log2-domain defer-max threshold: P <= 2^11 */

__device__ __forceinline__ unsigned short f2bf(float x) {
  union { float f; unsigned int u; } c; c.f = x;
  return (unsigned short)((c.u + 0x7fffu + ((c.u >> 16) & 1u)) >> 16);
}

__device__ __forceinline__ unsigned int cvtpk(float lo, float hi) {
  unsigned int r;
  asm("v_cvt_pk_bf16_f32 %0, %1, %2" : "=v"(r) : "v"(lo), "v"(hi));
  return r;
}

__device__ __forceinline__ short8 pk8(float4 a, float4 b) {
  union { unsigned int u[4]; short8 s; } r;
  r.u[0] = cvtpk(a.x, a.y);
  r.u[1] = cvtpk(a.z, a.w);
  r.u[2] = cvtpk(b.x, b.y);
  r.u[3] = cvtpk(b.z, b.w);
  return r.s;
}

__device__ __forceinline__ float fexp2(float x) {
#if __has_builtin(__builtin_amdgcn_exp2f)
  return __builtin_amdgcn_exp2f(x);
#else
  return exp2f(x);
#endif
}

// swap lanes 32-63 of a with lanes 0-31 of b; returns {newA, newB}
__device__ __forceinline__ uint2v plswap(unsigned int a, unsigned int b) {
#if __has_builtin(__builtin_amdgcn_permlane32_swap)
  return __builtin_amdgcn_permlane32_swap(a, b, false, false);
#else
  uint2v r;
  unsigned int sa = __shfl_xor(a, 32), sb = __shfl_xor(b, 32);
  int hi = (threadIdx.x & 63) >> 5;
  r[0] = hi ? sb : a;
  r[1] = hi ? b : sa;
  return r;
#endif
}

// ------------- prep: LDS-tiled W^T bf16 (x4), scaled bq -------------
__global__ __launch_bounds__(256) void prep_kernel(
    const float* __restrict__ wq, const float* __restrict__ wk,
    const float* __restrict__ wv, const float* __restrict__ wo,
    const float* __restrict__ bq, unsigned short* __restrict__ wt,
    float* __restrict__ bqs)
{
  __shared__ unsigned short tile[64][72];
  const int blk = blockIdx.x;       // 64 blocks: 4 mats x 4x4 tiles of 64x64
  const int mi = blk >> 4, tr = (blk >> 2) & 3, tc = blk & 3;
  const float* w = (mi == 0) ? wq : (mi == 1) ? wk : (mi == 2) ? wv : wo;
  const float scale = (mi == 0) ? QSCALE * LOG2E : 1.0f;
  const int t = threadIdx.x;
  {
    const int row = t >> 2, cg = (t & 3) * 16;
    const float* src = w + (size_t)(tr * 64 + row) * DMODEL + tc * 64 + cg;
    #pragma unroll
    for (int i = 0; i < 16; i += 4) {
      float4 f = *(const float4*)(src + i);
      tile[row][cg + i + 0] = f2bf(f.x * scale);
      tile[row][cg + i + 1] = f2bf(f.y * scale);
      tile[row][cg + i + 2] = f2bf(f.z * scale);
      tile[row][cg + i + 3] = f2bf(f.w * scale);
    }
  }
  __syncthreads();
  {
    const int nl = t & 63, kg = t >> 6;
    union { unsigned short us[8]; uint4 u; } o0, o1;
    #pragma unroll
    for (int i = 0; i < 8; i++) o0.us[i] = tile[kg * 16 + i][nl];
    #pragma unroll
    for (int i = 0; i < 8; i++) o1.us[i] = tile[kg * 16 + 8 + i][nl];
    unsigned short* dst = wt + mi * 65536 + (size_t)(tc * 64 + nl) * DMODEL + tr * 64 + kg * 16;
    *(uint4*)dst = o0.u;
    *(uint4*)(dst + 8) = o1.u;
  }
  if (blk == 0) bqs[t] = bq[t] * QSCALE * LOG2E;
}

// ------------- scan: compact-index for unmasked keys -------------
__global__ __launch_bounds__(256) void scan_kernel(
    const float* __restrict__ m, int* __restrict__ cidx,
    float* __restrict__ tailbias, int* __restrict__ nkp)
{
  __shared__ int ssum[256];
  const int t = threadIdx.x;
  float mv[8];
  float4 m0 = *(const float4*)(m + t * 8);
  float4 m1 = *(const float4*)(m + t * 8 + 4);
  mv[0]=m0.x; mv[1]=m0.y; mv[2]=m0.z; mv[3]=m0.w;
  mv[4]=m1.x; mv[5]=m1.y; mv[6]=m1.z; mv[7]=m1.w;
  int keep[8], cnt = 0;
  #pragma unroll
  for (int j = 0; j < 8; j++) { keep[j] = (mv[j] == 0.0f); cnt += keep[j]; }
  ssum[t] = cnt;
  __syncthreads();
  for (int off = 1; off < 256; off <<= 1) {
    int add = (t >= off) ? ssum[t - off] : 0;
    __syncthreads();
    ssum[t] += add;
    __syncthreads();
  }
  int base = ssum[t] - cnt;
  const int nk = ssum[255];
  #pragma unroll
  for (int j = 0; j < 8; j++) {
    cidx[t * 8 + j] = keep[j] ? base : -1;
    base += keep[j];
  }
  if (t == 0) nkp[0] = nk;
  if (t < 32) {
    int g = (nk & ~31) + t;
    tailbias[t] = (g < nk) ? 0.0f : NEGBIG;
  }
}

// ------------- fused QKV projection -------------
// z=0: Q -> qh [b][h][s][32] (pre-scaled); z=1: K -> kh compacted [b][h][cs][32];
// z=2: V -> vt compacted transposed [b][h][d][cs]
__global__ __launch_bounds__(256) void qkv_kernel(
    const float* __restrict__ q, const float* __restrict__ k,
    const float* __restrict__ v, const unsigned short* __restrict__ wt,
    const float* __restrict__ bqs, const float* __restrict__ bk,
    const float* __restrict__ bv, const int* __restrict__ cidx,
    unsigned short* __restrict__ qh, unsigned short* __restrict__ kh,
    unsigned short* __restrict__ vt)
{
  const int z = blockIdx.y;
  const int tile = blockIdx.x;  // 16 rows/tokens per block
  const int w = threadIdx.x >> 6, lane = threadIdx.x & 63;
  const int fr = lane & 15, hi4 = lane >> 4;

  f32x4 acc[4];
  #pragma unroll
  for (int n = 0; n < 4; n++) { acc[n][0]=0.f; acc[n][1]=0.f; acc[n][2]=0.f; acc[n][3]=0.f; }

  if (z < 2) {
    const float* x = z ? k : q;
    const unsigned short* wtz = wt + z * 65536;
    const float* xrow = x + (size_t)(tile * 16 + fr) * DMODEL;
    for (int kk = 0; kk < DMODEL; kk += 32) {
      float4 a0 = *(const float4*)(xrow + kk + 8 * hi4);
      float4 a1 = *(const float4*)(xrow + kk + 8 * hi4 + 4);
      short8 af = pk8(a0, a1);
      #pragma unroll
      for (int n = 0; n < 4; n++) {
        short8 bf = *(const short8*)(wtz + (size_t)(w * 64 + n * 16 + fr) * DMODEL + kk + 8 * hi4);
        acc[n] = __builtin_amdgcn_mfma_f32_16x16x32_bf16(af, bf, acc[n], 0, 0, 0);
      }
    }
    const float* bias = z ? bk : bqs;
    const int row0 = tile * 16 + hi4 * 4;
    #pragma unroll
    for (int n = 0; n < 4; n++) {
      const int col = w * 64 + n * 16 + fr;
      const float bb = bias[col];
      const int h = col >> 5, d = col & 31;
      #pragma unroll
      for (int j = 0; j < 4; j++) {
        const int r = row0 + j;
        const int b = r >> 11, s = r & 2047;
        unsigned short us = f2bf(acc[n][j] + bb);
        if (z == 0) {
          qh[(size_t)((b * NHEADS + h) * SEQ + s) * DHEAD + d] = us;
        } else {
          int cs = cidx[s];
          if (cs >= 0) kh[(size_t)((b * NHEADS + h) * SEQ + cs) * DHEAD + d] = us;
        }
      }
    }
  } else {
    const int tok = tile * 16 + fr;
    const float* xrow = v + (size_t)tok * DMODEL;
    const unsigned short* wtv = wt + 2 * 65536;
    for (int kk = 0; kk < DMODEL; kk += 32) {
      float4 b0 = *(const float4*)(xrow + kk + 8 * hi4);
      float4 b1 = *(const float4*)(xrow + kk + 8 * hi4 + 4);
      short8 bfx = pk8(b0, b1);
      #pragma unroll
      for (int n = 0; n < 4; n++) {
        short8 afw = *(const short8*)(wtv + (size_t)(w * 64 + n * 16 + fr) * DMODEL + kk + 8 * hi4);
        acc[n] = __builtin_amdgcn_mfma_f32_16x16x32_bf16(afw, bfx, acc[n], 0, 0, 0);
      }
    }
    const int b = tok >> 11, s = tok & 2047;
    const int cs = cidx[s];
    if (cs >= 0) {
      #pragma unroll
      for (int n = 0; n < 4; n++) {
        #pragma unroll
        for (int j = 0; j < 4; j++) {
          const int feat = w * 64 + n * 16 + hi4 * 4 + j;
          const int h = feat >> 5, d = feat & 31;
          vt[(size_t)((b * NHEADS + h) * DHEAD + d) * SEQ + cs] = f2bf(acc[n][j] + bv[feat]);
        }
      }
    }
  }
}

// ------------- flash attention over compacted keys -------------
template<bool MASKED>
__device__ __forceinline__ void attn_tile(
    const unsigned short* __restrict__ Kp, const unsigned short* __restrict__ Vp,
    int kt, const short8 qf0, const short8 qf1, const float* __restrict__ tailbias,
    int hi, int ql, f32x16& oacc, float& mrun, float& lrun)
{
  const unsigned short* krow = Kp + (size_t)(kt + ql) * DHEAD + 8 * hi;
  const short8 kf0 = *(const short8*)(krow);
  const short8 kf1 = *(const short8*)(krow + 16);
  f32x16 sacc;
  #pragma unroll
  for (int i = 0; i < 16; i++) sacc[i] = 0.0f;
  __builtin_amdgcn_s_setprio(1);
  sacc = __builtin_amdgcn_mfma_f32_32x32x16_bf16(kf0, qf0, sacc, 0, 0, 0);
  sacc = __builtin_amdgcn_mfma_f32_32x32x16_bf16(kf1, qf1, sacc, 0, 0, 0);
  __builtin_amdgcn_s_setprio(0);

  float p[16];
  if (MASKED) {
    const float4 t0 = *(const float4*)(tailbias + 4 * hi);
    const float4 t1 = *(const float4*)(tailbias + 4 * hi + 8);
    const float4 t2 = *(const float4*)(tailbias + 4 * hi + 16);
    const float4 t3 = *(const float4*)(tailbias + 4 * hi + 24);
    p[0]=sacc[0]+t0.x;  p[1]=sacc[1]+t0.y;  p[2]=sacc[2]+t0.z;  p[3]=sacc[3]+t0.w;
    p[4]=sacc[4]+t1.x;  p[5]=sacc[5]+t1.y;  p[6]=sacc[6]+t1.z;  p[7]=sacc[7]+t1.w;
    p[8]=sacc[8]+t2.x;  p[9]=sacc[9]+t2.y;  p[10]=sacc[10]+t2.z; p[11]=sacc[11]+t2.w;
    p[12]=sacc[12]+t3.x; p[13]=sacc[13]+t3.y; p[14]=sacc[14]+t3.z; p[15]=sacc[15]+t3.w;
  } else {
    #pragma unroll
    for (int i = 0; i < 16; i++) p[i] = sacc[i];
  }

  // local max via max3-fusable tree
  float x0 = fmaxf(fmaxf(p[0], p[1]), p[2]);
  float x1 = fmaxf(fmaxf(p[3], p[4]), p[5]);
  float x2 = fmaxf(fmaxf(p[6], p[7]), p[8]);
  float x3 = fmaxf(fmaxf(p[9], p[10]), p[11]);
  float x4 = fmaxf(fmaxf(p[12], p[13]), p[14]);
  float tmax = fmaxf(fmaxf(fmaxf(x0, x1), fmaxf(x2, x3)), fmaxf(x4, p[15]));

  // defer-max: skip rescale unless max grew past threshold (wave-uniform)
  if (!__all(tmax <= mrun + DEFER_THR)) {
    float pm = fmaxf(tmax, __shfl_xor(tmax, 32));
    float mnew = fmaxf(mrun, pm);
    float corr = fexp2(mrun - mnew);
    mrun = mnew;
    lrun *= corr;
    #pragma unroll
    for (int i = 0; i < 16; i++) oacc[i] *= corr;
  }

  float psum = 0.0f;
  #pragma unroll
  for (int i = 0; i < 16; i++) { p[i] = fexp2(p[i] - mrun); psum += p[i]; }
  lrun += psum;  // per-lane partial; pair-reduced in epilogue

  const unsigned int A0 = cvtpk(p[0], p[1]);
  const unsigned int A1 = cvtpk(p[2], p[3]);
  const unsigned int B0 = cvtpk(p[4], p[5]);
  const unsigned int B1 = cvtpk(p[6], p[7]);
  const unsigned int A2 = cvtpk(p[8], p[9]);
  const unsigned int A3 = cvtpk(p[10], p[11]);
  const unsigned int B2 = cvtpk(p[12], p[13]);
  const unsigned int B3 = cvtpk(p[14], p[15]);
  union { unsigned int u[4]; short8 s; } pb0, pb1;
  uint2v r0 = plswap(A0, B0); pb0.u[0] = r0[0]; pb0.u[2] = r0[1];
  uint2v r1 = plswap(A1, B1); pb0.u[1] = r1[0]; pb0.u[3] = r1[1];
  uint2v r2 = plswap(A2, B2); pb1.u[0] = r2[0]; pb1.u[2] = r2[1];
  uint2v r3 = plswap(A3, B3); pb1.u[1] = r3[0]; pb1.u[3] = r3[1];

  const short8 vf0 = *(const short8*)(Vp + kt + 8 * hi);
  const short8 vf1 = *(const short8*)(Vp + kt + 16 + 8 * hi);
  __builtin_amdgcn_s_setprio(1);
  oacc = __builtin_amdgcn_mfma_f32_32x32x16_bf16(vf0, pb0.s, oacc, 0, 0, 0);
  oacc = __builtin_amdgcn_mfma_f32_32x32x16_bf16(vf1, pb1.s, oacc, 0, 0, 0);
  __builtin_amdgcn_s_setprio(0);
}

__global__ __launch_bounds__(256) void attn_kernel(
    const unsigned short* __restrict__ qh, const unsigned short* __restrict__ kh,
    const unsigned short* __restrict__ vt, const float* __restrict__ tailbias,
    const int* __restrict__ nkp, unsigned short* __restrict__ attno)
{
  const int bid = blockIdx.x;
  const int L = (bid & 7) * 128 + (bid >> 3);  // XCD swizzle (1024 % 8 == 0)
  const int bh = L >> 4, qt = L & 15;
  const int w = threadIdx.x >> 6, lane = threadIdx.x & 63;
  const int ql = lane & 31, hi = lane >> 5;
  const int qrow = qt * 128 + w * 32 + ql;
  const unsigned short* Qp = qh + ((size_t)bh * SEQ + qrow) * DHEAD;
  const unsigned short* Kp = kh + (size_t)bh * SEQ * DHEAD;
  const unsigned short* Vp = vt + (size_t)bh * DHEAD * SEQ + (size_t)ql * SEQ;

  const short8 qf0 = *(const short8*)(Qp + 8 * hi);
  const short8 qf1 = *(const short8*)(Qp + 16 + 8 * hi);

  f32x16 oacc;
  #pragma unroll
  for (int i = 0; i < 16; i++) oacc[i] = 0.0f;
  float mrun = -1e30f, lrun = 0.0f;

  const int nk = *nkp;
  const int nfull = nk >> 5, ntail = nk & 31;

  for (int kt = 0; kt < nfull * 32; kt += 32)
    attn_tile<false>(Kp, Vp, kt, qf0, qf1, tailbias, hi, ql, oacc, mrun, lrun);
  if (ntail)
    attn_tile<true>(Kp, Vp, nfull * 32, qf0, qf1, tailbias, hi, ql, oacc, mrun, lrun);

  const float ltot = lrun + __shfl_xor(lrun, 32);
  const float inv = 1.0f / ltot;
  const int b = bh >> 3, h = bh & 7;
  unsigned short* orow = attno + ((size_t)(b * SEQ + qrow)) * DMODEL + h * DHEAD + 4 * hi;
  #pragma unroll
  for (int g = 0; g < 4; g++) {
    union { unsigned short us[4]; uint2 u2; } st;
    st.us[0] = f2bf(oacc[4 * g + 0] * inv);
    st.us[1] = f2bf(oacc[4 * g + 1] * inv);
    st.us[2] = f2bf(oacc[4 * g + 2] * inv);
    st.us[3] = f2bf(oacc[4 * g + 3] * inv);
    *(uint2*)(orow + 8 * g) = st.u2;
  }
}

// ------------- output projection -------------
__global__ __launch_bounds__(256) void oproj_kernel(
    const unsigned short* __restrict__ attno, const unsigned short* __restrict__ wto,
    const float* __restrict__ bo, float* __restrict__ out)
{
  const int tile = blockIdx.x;  // 16 rows per block
  const int w = threadIdx.x >> 6, lane = threadIdx.x & 63;
  const int fr = lane & 15, hi4 = lane >> 4;
  const unsigned short* arow = attno + (size_t)(tile * 16 + fr) * DMODEL;

  f32x4 acc[4];
  #pragma unroll
  for (int n = 0; n < 4; n++) { acc[n][0]=0.f; acc[n][1]=0.f; acc[n][2]=0.f; acc[n][3]=0.f; }

  for (int kk = 0; kk < DMODEL; kk += 32) {
    short8 af = *(const short8*)(arow + kk + 8 * hi4);
    #pragma unroll
    for (int n = 0; n < 4; n++) {
      short8 bf = *(const short8*)(wto + (size_t)(w * 64 + n * 16 + fr) * DMODEL + kk + 8 * hi4);
      acc[n] = __builtin_amdgcn_mfma_f32_16x16x32_bf16(af, bf, acc[n], 0, 0, 0);
    }
  }

  const int row0 = tile * 16 + hi4 * 4;
  #pragma unroll
  for (int n = 0; n < 4; n++) {
    const int col = w * 64 + n * 16 + fr;
    const float bb = bo[col];
    #pragma unroll
    for (int j = 0; j < 4; j++) {
      out[(size_t)(row0 + j) * DMODEL + col] = acc[n][j] + bb;
    }
  }
}

extern "C" void kernel_launch(void* const* d_in, const int* in_sizes, int n_in,
                              void* d_out, int out_size, void* d_ws, size_t ws_size,
                              hipStream_t stream) {
  const float* q  = (const float*)d_in[0];
  const float* k  = (const float*)d_in[1];
  const float* v  = (const float*)d_in[2];
  const float* m  = (const float*)d_in[3];
  const float* wq = (const float*)d_in[4];
  const float* bq = (const float*)d_in[5];
  const float* wk = (const float*)d_in[6];
  const float* bk = (const float*)d_in[7];
  const float* wv = (const float*)d_in[8];
  const float* bv = (const float*)d_in[9];
  const float* wo = (const float*)d_in[10];
  const float* bo = (const float*)d_in[11];
  float* out = (float*)d_out;

  char* ws = (char*)d_ws;
  unsigned short* wt    = (unsigned short*)ws;              // 4 x 256x256 bf16 (512 KB)
  float* bqs            = (float*)(ws + 524288);            // 256 f32
  float* tailbias       = (float*)(ws + 525312);            // 32 f32
  int*   nkp            = (int*)(ws + 525440);              // 1 int
  int*   cidx           = (int*)(ws + 526336);              // 2048 int
  unsigned short* qh    = (unsigned short*)(ws + 1048576);  // 8 MB
  unsigned short* kh    = qh + 4194304;                     // 8 MB (compacted rows)
  unsigned short* vt    = kh + 4194304;                     // 8 MB (compacted cols)
  unsigned short* attno = vt + 4194304;                     // 8 MB

  prep_kernel<<<dim3(64), dim3(256), 0, stream>>>(wq, wk, wv, wo, bq, wt, bqs);
  scan_kernel<<<dim3(1), dim3(256), 0, stream>>>(m, cidx, tailbias, nkp);
  qkv_kernel<<<dim3(1024, 3), dim3(256), 0, stream>>>(q, k, v, wt, bqs, bk, bv, cidx, qh, kh, vt);
  attn_kernel<<<dim3(1024), dim3(256), 0, stream>>>(qh, kh, vt, tailbias, nkp, attno);
  oproj_kernel<<<dim3(1024), dim3(256), 0, stream>>>(attno, wt + 3 * 65536, bo, out);
}

// Round 4
// 180.081 us; speedup vs baseline: 1.7332x; 1.3759x over previous
//
#include <hip/hip_runtime.h>

typedef short short8 __attribute__((ext_vector_type(8)));
typedef float f32x4 __attribute__((ext_vector_type(4)));
typedef float f32x16 __attribute__((ext_vector_type(16)));
typedef unsigned int uint2v __attribute__((ext_vector_type(2)));

#define NHEADS 8
#define DHEAD 32
#define DMODEL 256
#define SEQ 2048
#define QSCALE 0.17677669529663687f /* 1/sqrt(32) */
#define LOG2E 1.4426950408889634f
#define NEGBIG -1.4427e9f            /* -1e9 * log2e: underflows exp2 */
#define DEFER_THR 11.0f              /* log2-domain defer-max threshold */

__device__ __forceinline__ unsigned short f2bf(float x) {
  union { float f; unsigned int u; } c; c.f = x;
  return (unsigned short)((c.u + 0x7fffu + ((c.u >> 16) & 1u)) >> 16);
}

__device__ __forceinline__ unsigned int cvtpk(float lo, float hi) {
  unsigned int r;
  asm("v_cvt_pk_bf16_f32 %0, %1, %2" : "=v"(r) : "v"(lo), "v"(hi));
  return r;
}

__device__ __forceinline__ short8 pk8(float4 a, float4 b) {
  union { unsigned int u[4]; short8 s; } r;
  r.u[0] = cvtpk(a.x, a.y);
  r.u[1] = cvtpk(a.z, a.w);
  r.u[2] = cvtpk(b.x, b.y);
  r.u[3] = cvtpk(b.z, b.w);
  return r.s;
}

__device__ __forceinline__ float fexp2(float x) {
#if __has_builtin(__builtin_amdgcn_exp2f)
  return __builtin_amdgcn_exp2f(x);
#else
  return exp2f(x);
#endif
}

__device__ __forceinline__ uint2v plswap(unsigned int a, unsigned int b) {
#if __has_builtin(__builtin_amdgcn_permlane32_swap)
  return __builtin_amdgcn_permlane32_swap(a, b, false, false);
#else
  uint2v r;
  unsigned int sa = __shfl_xor(a, 32), sb = __shfl_xor(b, 32);
  int hi = (threadIdx.x & 63) >> 5;
  r[0] = hi ? sb : a;
  r[1] = hi ? b : sa;
  return r;
#endif
}

// swizzled LDS byte address: row-major [rows][256 bf16], 16B granule c
__device__ __forceinline__ int swz(int row, int c) {
  return row * 512 + ((c ^ (row & 7)) << 4);
}

// ------------- prep: W -> b-fragment-layout bf16 wt[mat][nt][kk][lane][8] -------------
__global__ __launch_bounds__(256) void prep_kernel(
    const float* __restrict__ wq, const float* __restrict__ wk,
    const float* __restrict__ wv, const float* __restrict__ wo,
    const float* __restrict__ bq, unsigned short* __restrict__ wt,
    float* __restrict__ bqs)
{
  __shared__ float tile[256][17];
  const int blk = blockIdx.x;       // 64 blocks: mat(4) x ntile(16)
  const int mi = blk >> 4, nt = blk & 15;
  const float* w = (mi == 0) ? wq : (mi == 1) ? wk : (mi == 2) ? wv : wo;
  const float scale = (mi == 0) ? QSCALE * LOG2E : 1.0f;
  const int t = threadIdx.x;
  {
    const float* src = w + (size_t)t * DMODEL + nt * 16;  // row k=t, 16 n-cols
    #pragma unroll
    for (int i = 0; i < 16; i += 4) {
      float4 f = *(const float4*)(src + i);
      tile[t][i + 0] = f.x; tile[t][i + 1] = f.y;
      tile[t][i + 2] = f.z; tile[t][i + 3] = f.w;
    }
  }
  __syncthreads();
  unsigned short* dst = wt + mi * 65536 + nt * 4096;
  #pragma unroll
  for (int gi = 0; gi < 2; gi++) {
    const int g = t * 2 + gi;       // granule: kk(8) x lane(64)
    const int kk = g >> 6, l = g & 63;
    const int fr = l & 15, hi4 = l >> 4;
    union { unsigned short us[8]; uint4 u; } o;
    #pragma unroll
    for (int j = 0; j < 8; j++)
      o.us[j] = f2bf(tile[kk * 32 + hi4 * 8 + j][fr] * scale);
    *(uint4*)(dst + g * 8) = o.u;
  }
  if (blk == 0) bqs[t] = bq[t] * QSCALE * LOG2E;
}

// ------------- scan: compact-index for unmasked keys -------------
__global__ __launch_bounds__(256) void scan_kernel(
    const float* __restrict__ m, int* __restrict__ cidx,
    float* __restrict__ tailbias, int* __restrict__ nkp)
{
  __shared__ int ssum[256];
  const int t = threadIdx.x;
  float mv[8];
  float4 m0 = *(const float4*)(m + t * 8);
  float4 m1 = *(const float4*)(m + t * 8 + 4);
  mv[0]=m0.x; mv[1]=m0.y; mv[2]=m0.z; mv[3]=m0.w;
  mv[4]=m1.x; mv[5]=m1.y; mv[6]=m1.z; mv[7]=m1.w;
  int keep[8], cnt = 0;
  #pragma unroll
  for (int j = 0; j < 8; j++) { keep[j] = (mv[j] == 0.0f); cnt += keep[j]; }
  ssum[t] = cnt;
  __syncthreads();
  for (int off = 1; off < 256; off <<= 1) {
    int add = (t >= off) ? ssum[t - off] : 0;
    __syncthreads();
    ssum[t] += add;
    __syncthreads();
  }
  int base = ssum[t] - cnt;
  const int nk = ssum[255];
  #pragma unroll
  for (int j = 0; j < 8; j++) {
    cidx[t * 8 + j] = keep[j] ? base : -1;
    base += keep[j];
  }
  if (t == 0) nkp[0] = nk;
  if (t < 32) {
    int g = (nk & ~31) + t;
    tailbias[t] = (g < nk) ? 0.0f : NEGBIG;
  }
}

// ------------- fused QKV projection: 64-row tiles, LDS-staged A -------------
// Outputs in attn fragment layouts (per bh, 2KB per 32-token tile):
//  Q/K: off = tile*1024 + (d>>4)*512 + ((d>>3)&1)*256 + (s&31)*8 + (d&7)
//  V^T: off = tile*1024 + ((cs>>4)&1)*512 + ((cs>>3)&1)*256 + d*8 + (cs&7)
__global__ __launch_bounds__(256) void qkv_kernel(
    const float* __restrict__ q, const float* __restrict__ k,
    const float* __restrict__ v, const unsigned short* __restrict__ wt,
    const float* __restrict__ bqs, const float* __restrict__ bk,
    const float* __restrict__ bv, const int* __restrict__ cidx,
    unsigned short* __restrict__ qf, unsigned short* __restrict__ kf,
    unsigned short* __restrict__ vf)
{
  __shared__ __align__(16) char alds[32768];
  const int z = blockIdx.y;
  const int tile = blockIdx.x;      // 64 tokens each
  const int t = threadIdx.x;
  const int w = t >> 6, lane = t & 63;
  const int fr = lane & 15, hi4 = lane >> 4;

  const float* x = (z == 0) ? q : (z == 1) ? k : v;
  const float* xbase = x + (size_t)tile * 64 * DMODEL;

  // stage 64x256 fp32 -> bf16 LDS, coalesced reads, swizzled writes
  #pragma unroll
  for (int i = 0; i < 8; i++) {
    const int gi = i * 256 + t;
    const int row = gi >> 5, c = gi & 31;
    const float4* src = (const float4*)(xbase + row * DMODEL + c * 8);
    float4 a0 = src[0], a1 = src[1];
    *(short8*)(alds + swz(row, c)) = pk8(a0, a1);
  }
  __syncthreads();

  f32x4 acc[4][4];
  #pragma unroll
  for (int mi = 0; mi < 4; mi++)
    #pragma unroll
    for (int ni = 0; ni < 4; ni++) { acc[mi][ni][0]=0.f; acc[mi][ni][1]=0.f; acc[mi][ni][2]=0.f; acc[mi][ni][3]=0.f; }

  const unsigned short* wz = wt + z * 65536 + (w * 4) * 4096;
  for (int kk = 0; kk < DMODEL; kk += 32) {
    short8 a[4], b[4];
    #pragma unroll
    for (int mi = 0; mi < 4; mi++)
      a[mi] = *(const short8*)(alds + swz(mi * 16 + fr, (kk >> 3) + hi4));
    #pragma unroll
    for (int ni = 0; ni < 4; ni++)
      b[ni] = *(const short8*)(wz + ni * 4096 + (kk >> 5) * 512 + lane * 8);
    #pragma unroll
    for (int mi = 0; mi < 4; mi++)
      #pragma unroll
      for (int ni = 0; ni < 4; ni++)
        acc[mi][ni] = __builtin_amdgcn_mfma_f32_16x16x32_bf16(a[mi], b[ni], acc[mi][ni], 0, 0, 0);
  }

  const float* bias = (z == 0) ? bqs : (z == 1) ? bk : bv;
  #pragma unroll
  for (int ni = 0; ni < 4; ni++) {
    const int f = w * 64 + ni * 16 + fr;
    const float bb = bias[f];
    const int h = f >> 5, d = f & 31;
    #pragma unroll
    for (int mi = 0; mi < 4; mi++) {
      #pragma unroll
      for (int j = 0; j < 4; j++) {
        const int token = tile * 64 + mi * 16 + hi4 * 4 + j;
        const int b_ = token >> 11, s = token & 2047;
        const unsigned short val = f2bf(acc[mi][ni][j] + bb);
        const size_t bhb = (size_t)(b_ * NHEADS + h) * 65536;
        if (z == 0) {
          qf[bhb + (s >> 5) * 1024 + (d >> 4) * 512 + ((d >> 3) & 1) * 256 + (s & 31) * 8 + (d & 7)] = val;
        } else {
          const int cs = cidx[s];
          if (cs >= 0) {
            if (z == 1)
              kf[bhb + (cs >> 5) * 1024 + (d >> 4) * 512 + ((d >> 3) & 1) * 256 + (cs & 31) * 8 + (d & 7)] = val;
            else
              vf[bhb + (cs >> 5) * 1024 + ((cs >> 4) & 1) * 512 + ((cs >> 3) & 1) * 256 + d * 8 + (cs & 7)] = val;
          }
        }
      }
    }
  }
}

// ------------- flash attention over compacted keys, fragment-layout loads -------------
template<bool MASKED>
__device__ __forceinline__ void attn_tile(
    const unsigned short* __restrict__ Kl, const unsigned short* __restrict__ Vl,
    int tb, const short8 qf0, const short8 qf1, const float* __restrict__ tailbias,
    int hi, f32x16& oacc, float& mrun, float& lrun)
{
  const short8 kf0 = *(const short8*)(Kl + tb);
  const short8 kf1 = *(const short8*)(Kl + tb + 512);
  f32x16 sacc;
  #pragma unroll
  for (int i = 0; i < 16; i++) sacc[i] = 0.0f;
  __builtin_amdgcn_s_setprio(1);
  sacc = __builtin_amdgcn_mfma_f32_32x32x16_bf16(kf0, qf0, sacc, 0, 0, 0);
  sacc = __builtin_amdgcn_mfma_f32_32x32x16_bf16(kf1, qf1, sacc, 0, 0, 0);
  __builtin_amdgcn_s_setprio(0);

  float p[16];
  if (MASKED) {
    const float4 t0 = *(const float4*)(tailbias + 4 * hi);
    const float4 t1 = *(const float4*)(tailbias + 4 * hi + 8);
    const float4 t2 = *(const float4*)(tailbias + 4 * hi + 16);
    const float4 t3 = *(const float4*)(tailbias + 4 * hi + 24);
    p[0]=sacc[0]+t0.x;  p[1]=sacc[1]+t0.y;  p[2]=sacc[2]+t0.z;  p[3]=sacc[3]+t0.w;
    p[4]=sacc[4]+t1.x;  p[5]=sacc[5]+t1.y;  p[6]=sacc[6]+t1.z;  p[7]=sacc[7]+t1.w;
    p[8]=sacc[8]+t2.x;  p[9]=sacc[9]+t2.y;  p[10]=sacc[10]+t2.z; p[11]=sacc[11]+t2.w;
    p[12]=sacc[12]+t3.x; p[13]=sacc[13]+t3.y; p[14]=sacc[14]+t3.z; p[15]=sacc[15]+t3.w;
  } else {
    #pragma unroll
    for (int i = 0; i < 16; i++) p[i] = sacc[i];
  }

  float x0 = fmaxf(fmaxf(p[0], p[1]), p[2]);
  float x1 = fmaxf(fmaxf(p[3], p[4]), p[5]);
  float x2 = fmaxf(fmaxf(p[6], p[7]), p[8]);
  float x3 = fmaxf(fmaxf(p[9], p[10]), p[11]);
  float x4 = fmaxf(fmaxf(p[12], p[13]), p[14]);
  float tmax = fmaxf(fmaxf(fmaxf(x0, x1), fmaxf(x2, x3)), fmaxf(x4, p[15]));

  if (!__all(tmax <= mrun + DEFER_THR)) {
    float pm = fmaxf(tmax, __shfl_xor(tmax, 32));
    float mnew = fmaxf(mrun, pm);
    float corr = fexp2(mrun - mnew);
    mrun = mnew;
    lrun *= corr;
    #pragma unroll
    for (int i = 0; i < 16; i++) oacc[i] *= corr;
  }

  float psum = 0.0f;
  #pragma unroll
  for (int i = 0; i < 16; i++) { p[i] = fexp2(p[i] - mrun); psum += p[i]; }
  lrun += psum;

  const unsigned int A0 = cvtpk(p[0], p[1]);
  const unsigned int A1 = cvtpk(p[2], p[3]);
  const unsigned int B0 = cvtpk(p[4], p[5]);
  const unsigned int B1 = cvtpk(p[6], p[7]);
  const unsigned int A2 = cvtpk(p[8], p[9]);
  const unsigned int A3 = cvtpk(p[10], p[11]);
  const unsigned int B2 = cvtpk(p[12], p[13]);
  const unsigned int B3 = cvtpk(p[14], p[15]);
  union { unsigned int u[4]; short8 s; } pb0, pb1;
  uint2v r0 = plswap(A0, B0); pb0.u[0] = r0[0]; pb0.u[2] = r0[1];
  uint2v r1 = plswap(A1, B1); pb0.u[1] = r1[0]; pb0.u[3] = r1[1];
  uint2v r2 = plswap(A2, B2); pb1.u[0] = r2[0]; pb1.u[2] = r2[1];
  uint2v r3 = plswap(A3, B3); pb1.u[1] = r3[0]; pb1.u[3] = r3[1];

  const short8 vf0 = *(const short8*)(Vl + tb);
  const short8 vf1 = *(const short8*)(Vl + tb + 512);
  __builtin_amdgcn_s_setprio(1);
  oacc = __builtin_amdgcn_mfma_f32_32x32x16_bf16(vf0, pb0.s, oacc, 0, 0, 0);
  oacc = __builtin_amdgcn_mfma_f32_32x32x16_bf16(vf1, pb1.s, oacc, 0, 0, 0);
  __builtin_amdgcn_s_setprio(0);
}

__global__ __launch_bounds__(256) void attn_kernel(
    const unsigned short* __restrict__ qf, const unsigned short* __restrict__ kfr,
    const unsigned short* __restrict__ vfr, const float* __restrict__ tailbias,
    const int* __restrict__ nkp, unsigned short* __restrict__ attno)
{
  const int bid = blockIdx.x;
  const int L = (bid & 7) * 128 + (bid >> 3);  // XCD swizzle (1024 % 8 == 0)
  const int bh = L >> 4, qt = L & 15;
  const int w = threadIdx.x >> 6, lane = threadIdx.x & 63;
  const int ql = lane & 31, hi = lane >> 5;
  const int qrow = qt * 128 + w * 32 + ql;
  const int loff = hi * 256 + ql * 8;
  const unsigned short* Qb = qf + (size_t)bh * 65536 + (size_t)(qt * 4 + w) * 1024 + loff;
  const unsigned short* Kl = kfr + (size_t)bh * 65536 + loff;
  const unsigned short* Vl = vfr + (size_t)bh * 65536 + loff;

  const short8 q0 = *(const short8*)(Qb);
  const short8 q1 = *(const short8*)(Qb + 512);

  f32x16 oacc;
  #pragma unroll
  for (int i = 0; i < 16; i++) oacc[i] = 0.0f;
  float mrun = -1e30f, lrun = 0.0f;

  const int nk = *nkp;
  const int nfull = nk >> 5, ntail = nk & 31;

  for (int ti = 0; ti < nfull; ti++)
    attn_tile<false>(Kl, Vl, ti * 1024, q0, q1, tailbias, hi, oacc, mrun, lrun);
  if (ntail)
    attn_tile<true>(Kl, Vl, nfull * 1024, q0, q1, tailbias, hi, oacc, mrun, lrun);

  const float ltot = lrun + __shfl_xor(lrun, 32);
  const float inv = 1.0f / ltot;
  const int b = bh >> 3, h = bh & 7;
  unsigned short* orow = attno + ((size_t)(b * SEQ + qrow)) * DMODEL + h * DHEAD + 4 * hi;
  #pragma unroll
  for (int g = 0; g < 4; g++) {
    union { unsigned short us[4]; uint2 u2; } st;
    st.us[0] = f2bf(oacc[4 * g + 0] * inv);
    st.us[1] = f2bf(oacc[4 * g + 1] * inv);
    st.us[2] = f2bf(oacc[4 * g + 2] * inv);
    st.us[3] = f2bf(oacc[4 * g + 3] * inv);
    *(uint2*)(orow + 8 * g) = st.u2;
  }
}

// ------------- output projection: 32-row tiles, LDS-staged A -------------
__global__ __launch_bounds__(256) void oproj_kernel(
    const unsigned short* __restrict__ attno, const unsigned short* __restrict__ wto,
    const float* __restrict__ bo, float* __restrict__ out)
{
  __shared__ __align__(16) char alds[16384];
  const int tile = blockIdx.x;      // 512 blocks, 32 tokens each
  const int t = threadIdx.x;
  const int w = t >> 6, lane = t & 63;
  const int fr = lane & 15, hi4 = lane >> 4;
  const unsigned short* abase = attno + (size_t)tile * 32 * DMODEL;

  #pragma unroll
  for (int i = 0; i < 4; i++) {
    const int gi = i * 256 + t;
    const int row = gi >> 5, c = gi & 31;
    uint4 u = *(const uint4*)(abase + row * DMODEL + c * 8);
    *(uint4*)(alds + swz(row, c)) = u;
  }
  __syncthreads();

  f32x4 acc[2][4];
  #pragma unroll
  for (int mi = 0; mi < 2; mi++)
    #pragma unroll
    for (int ni = 0; ni < 4; ni++) { acc[mi][ni][0]=0.f; acc[mi][ni][1]=0.f; acc[mi][ni][2]=0.f; acc[mi][ni][3]=0.f; }

  const unsigned short* wz = wto + (w * 4) * 4096;
  for (int kk = 0; kk < DMODEL; kk += 32) {
    short8 a[2], b[4];
    #pragma unroll
    for (int mi = 0; mi < 2; mi++)
      a[mi] = *(const short8*)(alds + swz(mi * 16 + fr, (kk >> 3) + hi4));
    #pragma unroll
    for (int ni = 0; ni < 4; ni++)
      b[ni] = *(const short8*)(wz + ni * 4096 + (kk >> 5) * 512 + lane * 8);
    #pragma unroll
    for (int mi = 0; mi < 2; mi++)
      #pragma unroll
      for (int ni = 0; ni < 4; ni++)
        acc[mi][ni] = __builtin_amdgcn_mfma_f32_16x16x32_bf16(a[mi], b[ni], acc[mi][ni], 0, 0, 0);
  }

  #pragma unroll
  for (int ni = 0; ni < 4; ni++) {
    const int f = w * 64 + ni * 16 + fr;
    const float bb = bo[f];
    #pragma unroll
    for (int mi = 0; mi < 2; mi++) {
      #pragma unroll
      for (int j = 0; j < 4; j++) {
        const int token = tile * 32 + mi * 16 + hi4 * 4 + j;
        out[(size_t)token * DMODEL + f] = acc[mi][ni][j] + bb;
      }
    }
  }
}

extern "C" void kernel_launch(void* const* d_in, const int* in_sizes, int n_in,
                              void* d_out, int out_size, void* d_ws, size_t ws_size,
                              hipStream_t stream) {
  const float* q  = (const float*)d_in[0];
  const float* k  = (const float*)d_in[1];
  const float* v  = (const float*)d_in[2];
  const float* m  = (const float*)d_in[3];
  const float* wq = (const float*)d_in[4];
  const float* bq = (const float*)d_in[5];
  const float* wk = (const float*)d_in[6];
  const float* bk = (const float*)d_in[7];
  const float* wv = (const float*)d_in[8];
  const float* bv = (const float*)d_in[9];
  const float* wo = (const float*)d_in[10];
  const float* bo = (const float*)d_in[11];
  float* out = (float*)d_out;

  char* ws = (char*)d_ws;
  unsigned short* wt    = (unsigned short*)ws;              // 4 x 256x256 bf16 frag-layout (512 KB)
  float* bqs            = (float*)(ws + 524288);            // 256 f32
  float* tailbias       = (float*)(ws + 525312);            // 32 f32
  int*   nkp            = (int*)(ws + 525440);              // 1 int
  int*   cidx           = (int*)(ws + 526336);              // 2048 int
  unsigned short* qf    = (unsigned short*)(ws + 1048576);  // 8 MB frag layout
  unsigned short* kfr   = qf + 4194304;                     // 8 MB frag layout (compacted)
  unsigned short* vfr   = kfr + 4194304;                    // 8 MB frag layout (compacted, V^T)
  unsigned short* attno = vfr + 4194304;                    // 8 MB row-major

  prep_kernel<<<dim3(64), dim3(256), 0, stream>>>(wq, wk, wv, wo, bq, wt, bqs);
  scan_kernel<<<dim3(1), dim3(256), 0, stream>>>(m, cidx, tailbias, nkp);
  qkv_kernel<<<dim3(256, 3), dim3(256), 0, stream>>>(q, k, v, wt, bqs, bk, bv, cidx, qf, kfr, vfr);
  attn_kernel<<<dim3(1024), dim3(256), 0, stream>>>(qf, kfr, vfr, tailbias, nkp, attno);
  oproj_kernel<<<dim3(512), dim3(256), 0, stream>>>(attno, wt + 3 * 65536, bo, out);
}